// Round 5
// baseline (237.143 us; speedup 1.0000x reference)
//
#include <hip/hip_runtime.h>
#include <math.h>

#define T_TOKENS 8192
#define NEXP 64
#define HID 2048
#define NITER 30
#define SINK_BLOCKS 32
#define KSEG 4               // split-K segments
#define WREG 131072          // bf16 elements per W region (64 x 2048)

typedef __bf16 bf16_t;
typedef bf16_t bf16x8 __attribute__((ext_vector_type(8)));
typedef float  f32x4  __attribute__((ext_vector_type(4)));

__device__ __forceinline__ void gload_lds16(const void* g, void* l) {
    __builtin_amdgcn_global_load_lds(
        (const __attribute__((address_space(1))) unsigned int*)g,
        (__attribute__((address_space(3))) unsigned int*)l, 16, 0, 0);
}

// ---------------------------------------------------------------------------
// Kernel 0: W (64x2048 f32) -> hi/lo bf16, per-64k-chunk quad-XOR-swizzled,
// linear in the exact order gemm's global_load_lds consumes.
// ---------------------------------------------------------------------------
__global__ __launch_bounds__(256)
void prep_whl(const float* __restrict__ W, bf16_t* __restrict__ wsw)
{
    int gid = blockIdx.x * 256 + threadIdx.x;   // 0..32767
    int region = gid >> 14;                     // 0 = hi, 1 = lo
    int qid = gid & 16383;
    int c = qid >> 9, L = qid & 511;
    int r = L >> 3, slot = L & 7;
    int qi = slot ^ (r & 7);
    const float* src = W + (size_t)r * HID + c * 64 + qi * 8;
    float4 v0 = *(const float4*)src;
    float4 v1 = *(const float4*)(src + 4);
    float x[8] = {v0.x, v0.y, v0.z, v0.w, v1.x, v1.y, v1.z, v1.w};
    bf16x8 q;
#pragma unroll
    for (int i = 0; i < 8; i++) {
        bf16_t h = (bf16_t)x[i];
        q[i] = (region == 0) ? h : (bf16_t)(x[i] - (float)h);
    }
    *(bf16x8*)(wsw + (size_t)region * WREG + (size_t)qid * 8) = q;
}

// ---------------------------------------------------------------------------
// Kernel 1: split-K(4) MFMA GEMM. 1024 blocks x 256 thr (4 waves).
// Block: 32 tokens x 64 experts x K-quarter 512 (8 chunks of 64).
// 3 blocks/CU (launch_bounds 256,3; LDS 48KB) -> 3 independent barrier groups
// overlap per-chunk vmcnt(0) drains. All staging via global_load_lds(16B).
// 3-term split-bf16: C = Ah*Wh + Ah*Wl + Al*Wh. Plain-store to part[ks][t][e].
// ---------------------------------------------------------------------------
__global__ __launch_bounds__(256, 3)
void gemm_splitk(const float* __restrict__ A, const bf16_t* __restrict__ Wq,
                 float* __restrict__ part)
{
    __shared__ float  sA[2][32 * 64];       // 8 KB x2 (raw f32, swizzled chunks)
    __shared__ bf16_t sW[2][2][64 * 64];    // 8 KB x4 (hi/lo bf16, swizzled)

    const int tid = threadIdx.x, lane = tid & 63, wv = tid >> 6;
    const int ks   = blockIdx.x & 3;
    const int tok0 = (blockIdx.x >> 2) * 32;
    const int mgrp = wv >> 1, ngrp = wv & 1;
    const int g = lane >> 4, m = lane & 15;
    const int arow = mgrp * 16 + m;
    const int m7 = m & 7;

    f32x4 acc0 = {0.f, 0.f, 0.f, 0.f}, acc1 = {0.f, 0.f, 0.f, 0.f};

    // staging maps (2 A-instrs + 4 W-instrs per wave per chunk)
    int ap[2], acs[2];
#pragma unroll
    for (int j = 0; j < 2; j++) {
        int p = (wv * 2 + j) * 64 + lane;          // 16B-position 0..511
        ap[j] = p;
        int r = p >> 4, slot = p & 15;
        acs[j] = slot ^ (r & 7);                   // swizzled source chunk in row
    }

#define STAGE_CHUNK(cc, dst)                                                    \
    {                                                                           \
        const int _cc = (cc);                                                   \
        _Pragma("unroll")                                                       \
        for (int j = 0; j < 2; j++) {                                           \
            int r = ap[j] >> 4;                                                 \
            const float* src = A + (size_t)(tok0 + r) * HID + ks * 512          \
                             + _cc * 64 + acs[j] * 4;                           \
            gload_lds16(src, &sA[dst][(wv * 2 + j) * 256]);                     \
        }                                                                       \
        const size_t chb = ((size_t)(ks * 8 + _cc) * 512) * 8;                  \
        _Pragma("unroll")                                                       \
        for (int j = 0; j < 2; j++) {                                           \
            size_t q8 = chb + (size_t)((wv * 2 + j) * 64 + lane) * 8;           \
            gload_lds16(Wq + q8,        &sW[dst][0][(wv * 2 + j) * 512]);       \
            gload_lds16(Wq + WREG + q8, &sW[dst][1][(wv * 2 + j) * 512]);       \
        }                                                                       \
    }

    STAGE_CHUNK(0, 0);
    __syncthreads();

    for (int cc = 0; cc < 8; ++cc) {
        const int buf = cc & 1, nb = buf ^ 1;
        if (cc + 1 < 8) STAGE_CHUNK(cc + 1, nb);

        const float*  sAc = sA[buf];
        const bf16_t* sWh = sW[buf][0];
        const bf16_t* sWl = sW[buf][1];
#pragma unroll
        for (int k32 = 0; k32 < 2; ++k32) {
            int s0 = (k32 * 8 + g * 2) ^ m7;
            float4 x0 = *(const float4*)&sAc[arow * 64 + s0 * 4];
            float4 x1 = *(const float4*)&sAc[arow * 64 + (s0 ^ 1) * 4];
            float xs[8] = {x0.x, x0.y, x0.z, x0.w, x1.x, x1.y, x1.z, x1.w};
            bf16x8 fAh, fAl;
#pragma unroll
            for (int i = 0; i < 8; i++) {
                bf16_t h = (bf16_t)xs[i];
                fAh[i] = h; fAl[i] = (bf16_t)(xs[i] - (float)h);
            }
            const int q = k32 * 4 + g;
            {
                int off = (ngrp * 32 + m) * 64 + (q ^ m7) * 8;
                bf16x8 fWh = *(const bf16x8*)&sWh[off];
                bf16x8 fWl = *(const bf16x8*)&sWl[off];
                acc0 = __builtin_amdgcn_mfma_f32_16x16x32_bf16(fAh, fWh, acc0, 0, 0, 0);
                acc0 = __builtin_amdgcn_mfma_f32_16x16x32_bf16(fAh, fWl, acc0, 0, 0, 0);
                acc0 = __builtin_amdgcn_mfma_f32_16x16x32_bf16(fAl, fWh, acc0, 0, 0, 0);
            }
            {
                int off = (ngrp * 32 + 16 + m) * 64 + (q ^ m7) * 8;
                bf16x8 fWh = *(const bf16x8*)&sWh[off];
                bf16x8 fWl = *(const bf16x8*)&sWl[off];
                acc1 = __builtin_amdgcn_mfma_f32_16x16x32_bf16(fAh, fWh, acc1, 0, 0, 0);
                acc1 = __builtin_amdgcn_mfma_f32_16x16x32_bf16(fAh, fWl, acc1, 0, 0, 0);
                acc1 = __builtin_amdgcn_mfma_f32_16x16x32_bf16(fAl, fWh, acc1, 0, 0, 0);
            }
        }
        __syncthreads();
    }

    float* pb = part + (size_t)ks * T_TOKENS * 64;
#pragma unroll
    for (int i = 0; i < 4; i++) {
        int t = tok0 + mgrp * 16 + g * 4 + i;     // C: row=(lane>>4)*4+reg
        pb[(size_t)t * 64 + ngrp * 32 + m]      = acc0[i];   // col=lane&15
        pb[(size_t)t * 64 + ngrp * 32 + 16 + m] = acc1[i];
    }
#undef STAGE_CHUNK
}

// ---------------------------------------------------------------------------
// Kernel 2: persistent sinkhorn, 32 blocks x 256 thr = 1 token/thread.
// Load phase fuses split-K(4) reduce + logits + sigmoid stores, and builds a
// c-TRANSPOSED LDS tile once (per-iter colsum = contiguous b128 reads +
// broadcast d0 reads; no per-iter transpose). Cross-block sync: ONE hop/iter
// - publish 64 partials (agent-relaxed), readers value-signal on the data
// (0xAA poison < 0, partials > 0), full coalesced re-gather per poll round.
// ---------------------------------------------------------------------------
__global__ __launch_bounds__(256, 1)
void sinkhorn_v5(const float* __restrict__ part,
                 float* __restrict__ out,
                 float* __restrict__ sd)      // 30*32*64 partial slots
{
    __shared__ float tileT[64][260];    // [expert][token_local], pad 4 -> 2-way free
    __shared__ float d0_lds[256];
    __shared__ float d1_lds[64];
    __shared__ float pl[4][64];
    const int tid = threadIdx.x, bid = blockIdx.x;
    const int t = bid * 256 + tid;

    float* logits = out;
    float* aff    = out + (size_t)T_TOKENS * 64;
    float* idx    = out + (size_t)2 * T_TOKENS * 64;

    // --- fused load: reduce 4 K-segments, emit logits+affinities, build c
    float c[64];
#pragma unroll
    for (int e4 = 0; e4 < 16; e4++) {
        float4 v = *(const float4*)(part + (size_t)t * 64 + e4 * 4);
#pragma unroll
        for (int s = 1; s < KSEG; s++) {
            float4 p = *(const float4*)(part + (size_t)s * T_TOKENS * 64
                                             + (size_t)t * 64 + e4 * 4);
            v.x += p.x; v.y += p.y; v.z += p.z; v.w += p.w;
        }
        *(float4*)(logits + (size_t)t * 64 + e4 * 4) = v;
        float4 sg;
        sg.x = (v.x >= 0.f) ? 1.f / (1.f + expf(-v.x)) : expf(v.x) / (1.f + expf(v.x));
        sg.y = (v.y >= 0.f) ? 1.f / (1.f + expf(-v.y)) : expf(v.y) / (1.f + expf(v.y));
        sg.z = (v.z >= 0.f) ? 1.f / (1.f + expf(-v.z)) : expf(v.z) / (1.f + expf(v.z));
        sg.w = (v.w >= 0.f) ? 1.f / (1.f + expf(-v.w)) : expf(v.w) / (1.f + expf(v.w));
        *(float4*)(aff + (size_t)t * 64 + e4 * 4) = sg;
        c[e4 * 4 + 0] = expf(v.x);
        c[e4 * 4 + 1] = expf(v.y);
        c[e4 * 4 + 2] = expf(v.z);
        c[e4 * 4 + 3] = expf(v.w);
    }
    // transposed tile (once): instr e writes 64 consecutive tids -> conflict-free
#pragma unroll
    for (int e = 0; e < 64; e++) tileT[e][tid] = c[e];
    if (tid < 64) d1_lds[tid] = 1.0f;
    __syncthreads();

    const int pe = tid & 63, pq = tid >> 6;   // phase-2 mapping: expert, quarter
    float d0 = 0.f;

    for (int iter = 0; iter < NITER; ++iter) {
        // phase 1: d0[t] = (1/T) / (sum_e d1[e]*c[e] + eps)
        float s = 0.f;
#pragma unroll
        for (int e4 = 0; e4 < 16; e4++) {
            float4 dv = *(const float4*)(&d1_lds[e4 * 4]);
            s = fmaf(c[e4 * 4 + 0], dv.x, s);
            s = fmaf(c[e4 * 4 + 1], dv.y, s);
            s = fmaf(c[e4 * 4 + 2], dv.z, s);
            s = fmaf(c[e4 * 4 + 3], dv.w, s);
        }
        d0 = (1.0f / 8192.0f) / (s + 1e-8f);
        d0_lds[tid] = d0;
        __syncthreads();

        // phase 2: colsum[pe] over 64 tokens: contiguous c-reads + broadcast d0
        float cs = 0.f;
        const float* rowp = &tileT[pe][pq * 64];
        const float* d0p  = &d0_lds[pq * 64];
#pragma unroll
        for (int j = 0; j < 16; j++) {
            float4 cv = *(const float4*)(rowp + j * 4);
            float4 dv = *(const float4*)(d0p + j * 4);
            cs = fmaf(cv.x, dv.x, cs);
            cs = fmaf(cv.y, dv.y, cs);
            cs = fmaf(cv.z, dv.z, cs);
            cs = fmaf(cv.w, dv.w, cs);
        }
        pl[pq][pe] = cs;
        __syncthreads();

        // cross-block: publish partial; value-signal gather (one hop)
        if (tid < 64) {
            float S = pl[0][tid] + pl[1][tid] + pl[2][tid] + pl[3][tid];
            __hip_atomic_store(&sd[(size_t)(iter * SINK_BLOCKS + bid) * 64 + tid], S,
                               __ATOMIC_RELAXED, __HIP_MEMORY_SCOPE_AGENT);
            const float* base = sd + (size_t)iter * SINK_BLOCKS * 64 + tid;
            float v[SINK_BLOCKS];
            bool ok = false; int guard = 0;
            while (!ok && guard++ < (1 << 20)) {
                ok = true;
#pragma unroll
                for (int b = 0; b < SINK_BLOCKS; b++)
                    v[b] = __hip_atomic_load(base + b * 64, __ATOMIC_RELAXED,
                                             __HIP_MEMORY_SCOPE_AGENT);
#pragma unroll
                for (int b = 0; b < SINK_BLOCKS; b++) ok = ok && (v[b] > 0.f);
            }
            float S2 = 0.f;
#pragma unroll
            for (int b = 0; b < SINK_BLOCKS; b++) S2 += v[b];
            d1_lds[tid] = (1.0f / 64.0f) / (S2 + 1e-8f);
        }
        __syncthreads();
    }

    // argmax_e of d1[e]*c[e]*d0 (first max wins, like jnp.argmax)
    float best = -1.0f; int bi = 0;
#pragma unroll
    for (int e4 = 0; e4 < 16; e4++) {
        float4 dv = *(const float4*)(&d1_lds[e4 * 4]);
        float vv0 = (dv.x * c[e4 * 4 + 0]) * d0;
        float vv1 = (dv.y * c[e4 * 4 + 1]) * d0;
        float vv2 = (dv.z * c[e4 * 4 + 2]) * d0;
        float vv3 = (dv.w * c[e4 * 4 + 3]) * d0;
        if (vv0 > best) { best = vv0; bi = e4 * 4 + 0; }
        if (vv1 > best) { best = vv1; bi = e4 * 4 + 1; }
        if (vv2 > best) { best = vv2; bi = e4 * 4 + 2; }
        if (vv3 > best) { best = vv3; bi = e4 * 4 + 3; }
    }
    idx[t] = (float)bi;
}

extern "C" void kernel_launch(void* const* d_in, const int* in_sizes, int n_in,
                              void* d_out, int out_size, void* d_ws, size_t ws_size,
                              hipStream_t stream)
{
    (void)in_sizes; (void)n_in; (void)out_size; (void)ws_size;
    const float* hs = (const float*)d_in[0];   // 8192 x 2048 f32
    const float* W  = (const float*)d_in[1];   // 64 x 2048 f32
    float* out      = (float*)d_out;           // [logits | affinities | idx]

    bf16_t* wsw  = (bf16_t*)d_ws;                    // 512 KB prepped W (hi|lo)
    float*  part = (float*)d_ws + 131072;            // 8 MB: part[4][8192][64]
    float*  sd   = part + (size_t)KSEG * T_TOKENS * 64;  // 240 KB sink slots

    prep_whl<<<128, 256, 0, stream>>>(W, wsw);
    gemm_splitk<<<1024, 256, 0, stream>>>(hs, wsw, part);
    sinkhorn_v5<<<SINK_BLOCKS, 256, 0, stream>>>(part, out, sd);
}

// Round 6
// 235.676 us; speedup vs baseline: 1.0062x; 1.0062x over previous
//
#include <hip/hip_runtime.h>
#include <math.h>

#define T_TOKENS 8192
#define NEXP 64
#define HID 2048
#define NITER 30
#define SINK_BLOCKS 32
#define WREG 131072          // bf16 elements per W region (64 x 2048)

typedef __bf16 bf16_t;
typedef bf16_t bf16x8 __attribute__((ext_vector_type(8)));
typedef float  f32x4  __attribute__((ext_vector_type(4)));

__device__ __forceinline__ void gload_lds16(const void* g, void* l) {
    __builtin_amdgcn_global_load_lds(
        (const __attribute__((address_space(1))) unsigned int*)g,
        (__attribute__((address_space(3))) unsigned int*)l, 16, 0, 0);
}

// ---------------------------------------------------------------------------
// Kernel 0: W (64x2048 f32) -> hi/lo bf16, per-64k-chunk quad-XOR-swizzled,
// linear in the exact order gemm's global_load_lds consumes.
// ---------------------------------------------------------------------------
__global__ __launch_bounds__(256)
void prep_whl(const float* __restrict__ W, bf16_t* __restrict__ wsw)
{
    int gid = blockIdx.x * 256 + threadIdx.x;   // 0..32767
    int region = gid >> 14;                     // 0 = hi, 1 = lo
    int qid = gid & 16383;
    int c = qid >> 9, L = qid & 511;
    int r = L >> 3, slot = L & 7;
    int qi = slot ^ (r & 7);
    const float* src = W + (size_t)r * HID + c * 64 + qi * 8;
    float4 v0 = *(const float4*)src;
    float4 v1 = *(const float4*)(src + 4);
    float x[8] = {v0.x, v0.y, v0.z, v0.w, v1.x, v1.y, v1.z, v1.w};
    bf16x8 q;
#pragma unroll
    for (int i = 0; i < 8; i++) {
        bf16_t h = (bf16_t)x[i];
        q[i] = (region == 0) ? h : (bf16_t)(x[i] - (float)h);
    }
    *(bf16x8*)(wsw + (size_t)region * WREG + (size_t)qid * 8) = q;
}

// ---------------------------------------------------------------------------
// Kernel 1: split-K(2) MFMA GEMM — EXACT r4 configuration (control; next
// profile should surface its counters). 512 blocks x 256 thr (4 waves).
// Block: 32 tokens x 64 experts x K-half 1024 (16 chunks of 64).
// ---------------------------------------------------------------------------
__global__ __launch_bounds__(256, 2)
void gemm_splitk(const float* __restrict__ A, const bf16_t* __restrict__ Wq,
                 float* __restrict__ part)
{
    __shared__ float  sA[2][32 * 64];       // 8 KB x2 (raw f32, swizzled chunks)
    __shared__ bf16_t sW[2][2][64 * 64];    // 8 KB x4 (hi/lo bf16, swizzled)

    const int tid = threadIdx.x, lane = tid & 63, wv = tid >> 6;
    const int ks   = blockIdx.x & 1;
    const int tok0 = (blockIdx.x >> 1) * 32;
    const int mgrp = wv >> 1, ngrp = wv & 1;
    const int g = lane >> 4, m = lane & 15;
    const int arow = mgrp * 16 + m;
    const int m7 = m & 7;

    f32x4 acc0 = {0.f, 0.f, 0.f, 0.f}, acc1 = {0.f, 0.f, 0.f, 0.f};

    int ap[2], acs[2];
#pragma unroll
    for (int j = 0; j < 2; j++) {
        int p = (wv * 2 + j) * 64 + lane;          // 16B-position 0..511
        ap[j] = p;
        int r = p >> 4, slot = p & 15;
        acs[j] = slot ^ (r & 7);                   // swizzled source chunk in row
    }

#define STAGE_CHUNK(cc, dst)                                                    \
    {                                                                           \
        const int _cc = (cc);                                                   \
        _Pragma("unroll")                                                       \
        for (int j = 0; j < 2; j++) {                                           \
            int r = ap[j] >> 4;                                                 \
            const float* src = A + (size_t)(tok0 + r) * HID + ks * 1024         \
                             + _cc * 64 + acs[j] * 4;                           \
            gload_lds16(src, &sA[dst][(wv * 2 + j) * 256]);                     \
        }                                                                       \
        const size_t chb = ((size_t)(ks * 16 + _cc) * 512) * 8;                 \
        _Pragma("unroll")                                                       \
        for (int j = 0; j < 2; j++) {                                           \
            size_t q8 = chb + (size_t)((wv * 2 + j) * 64 + lane) * 8;           \
            gload_lds16(Wq + q8,        &sW[dst][0][(wv * 2 + j) * 512]);       \
            gload_lds16(Wq + WREG + q8, &sW[dst][1][(wv * 2 + j) * 512]);       \
        }                                                                       \
    }

    STAGE_CHUNK(0, 0);
    __syncthreads();

    for (int cc = 0; cc < 16; ++cc) {
        const int buf = cc & 1, nb = buf ^ 1;
        if (cc + 1 < 16) STAGE_CHUNK(cc + 1, nb);

        const float*  sAc = sA[buf];
        const bf16_t* sWh = sW[buf][0];
        const bf16_t* sWl = sW[buf][1];
#pragma unroll
        for (int k32 = 0; k32 < 2; ++k32) {
            int s0 = (k32 * 8 + g * 2) ^ m7;
            float4 x0 = *(const float4*)&sAc[arow * 64 + s0 * 4];
            float4 x1 = *(const float4*)&sAc[arow * 64 + (s0 ^ 1) * 4];
            float xs[8] = {x0.x, x0.y, x0.z, x0.w, x1.x, x1.y, x1.z, x1.w};
            bf16x8 fAh, fAl;
#pragma unroll
            for (int i = 0; i < 8; i++) {
                bf16_t h = (bf16_t)xs[i];
                fAh[i] = h; fAl[i] = (bf16_t)(xs[i] - (float)h);
            }
            const int q = k32 * 4 + g;
            {
                int off = (ngrp * 32 + m) * 64 + (q ^ m7) * 8;
                bf16x8 fWh = *(const bf16x8*)&sWh[off];
                bf16x8 fWl = *(const bf16x8*)&sWl[off];
                acc0 = __builtin_amdgcn_mfma_f32_16x16x32_bf16(fAh, fWh, acc0, 0, 0, 0);
                acc0 = __builtin_amdgcn_mfma_f32_16x16x32_bf16(fAh, fWl, acc0, 0, 0, 0);
                acc0 = __builtin_amdgcn_mfma_f32_16x16x32_bf16(fAl, fWh, acc0, 0, 0, 0);
            }
            {
                int off = (ngrp * 32 + 16 + m) * 64 + (q ^ m7) * 8;
                bf16x8 fWh = *(const bf16x8*)&sWh[off];
                bf16x8 fWl = *(const bf16x8*)&sWl[off];
                acc1 = __builtin_amdgcn_mfma_f32_16x16x32_bf16(fAh, fWh, acc1, 0, 0, 0);
                acc1 = __builtin_amdgcn_mfma_f32_16x16x32_bf16(fAh, fWl, acc1, 0, 0, 0);
                acc1 = __builtin_amdgcn_mfma_f32_16x16x32_bf16(fAl, fWh, acc1, 0, 0, 0);
            }
        }
        __syncthreads();
    }

    float* pb = part + (size_t)ks * T_TOKENS * 64;
#pragma unroll
    for (int i = 0; i < 4; i++) {
        int t = tok0 + mgrp * 16 + g * 4 + i;     // C: row=(lane>>4)*4+reg
        pb[(size_t)t * 64 + ngrp * 32 + m]      = acc0[i];   // col=lane&15
        pb[(size_t)t * 64 + ngrp * 32 + 16 + m] = acc1[i];
    }
#undef STAGE_CHUNK
}

// ---------------------------------------------------------------------------
// Kernel 2: persistent sinkhorn, 32 blocks x 256 thr = 1 token/thread.
// Hierarchical value-signaled all-reduce per iter (no flags, no fences):
//   stage A: every block publishes 64 partials (agent relaxed)
//   stage B: 8 leader blocks poll-gather their group of 4 (value-signal on the
//            data itself: partials > 0, 0xAA poison < 0), publish group sums
//   stage C: all blocks poll-gather the 8 leader slots, compute d1.
// Poll traffic: 256 (leaders) / 512 (readers) loads per round vs r3/r5's 2048.
// Block-local colsum: c-transposed tile, stride 261 (5*pe mod 32 bijective ->
// 2-way = free), contiguous b128 c-reads + broadcast d0 reads.
// ---------------------------------------------------------------------------
__global__ __launch_bounds__(256, 1)
void sinkhorn_v6(const float* __restrict__ part,
                 float* __restrict__ out,
                 float* __restrict__ sd1,     // 30*32*64 block partials
                 float* __restrict__ sd2)     // 30*8*64 leader group sums
{
    __shared__ float tileT[64][261];    // [expert][token_local]
    __shared__ float d0_lds[256];
    __shared__ float d1_lds[64];
    __shared__ float pl[4][64];
    const int tid = threadIdx.x, bid = blockIdx.x;
    const int t = bid * 256 + tid;

    float* logits = out;
    float* aff    = out + (size_t)T_TOKENS * 64;
    float* idx    = out + (size_t)2 * T_TOKENS * 64;

    const float* p0 = part + (size_t)t * 64;
    const float* p1 = part + (size_t)T_TOKENS * 64 + (size_t)t * 64;

    // --- fused load: split-K(2) reduce, logits + sigmoid stores, c regs, tile
    float c[64];
#pragma unroll
    for (int e4 = 0; e4 < 16; e4++) {
        float4 a = *(const float4*)(p0 + e4 * 4);
        float4 b = *(const float4*)(p1 + e4 * 4);
        float4 v = {a.x + b.x, a.y + b.y, a.z + b.z, a.w + b.w};
        *(float4*)(logits + (size_t)t * 64 + e4 * 4) = v;
        float4 sg;
        sg.x = (v.x >= 0.f) ? 1.f / (1.f + expf(-v.x)) : expf(v.x) / (1.f + expf(v.x));
        sg.y = (v.y >= 0.f) ? 1.f / (1.f + expf(-v.y)) : expf(v.y) / (1.f + expf(v.y));
        sg.z = (v.z >= 0.f) ? 1.f / (1.f + expf(-v.z)) : expf(v.z) / (1.f + expf(v.z));
        sg.w = (v.w >= 0.f) ? 1.f / (1.f + expf(-v.w)) : expf(v.w) / (1.f + expf(v.w));
        *(float4*)(aff + (size_t)t * 64 + e4 * 4) = sg;
        c[e4 * 4 + 0] = expf(v.x);
        c[e4 * 4 + 1] = expf(v.y);
        c[e4 * 4 + 2] = expf(v.z);
        c[e4 * 4 + 3] = expf(v.w);
    }
#pragma unroll
    for (int e = 0; e < 64; e++) tileT[e][tid] = c[e];   // (5e+tid)%32: 2-way, free
    if (tid < 64) d1_lds[tid] = 1.0f;
    __syncthreads();

    const int pe = tid & 63, pq = tid >> 6;
    float d0 = 0.f;

    for (int iter = 0; iter < NITER; ++iter) {
        // phase 1: d0[t] = (1/T) / (sum_e d1[e]*c[e] + eps)
        float s = 0.f;
#pragma unroll
        for (int e4 = 0; e4 < 16; e4++) {
            float4 dv = *(const float4*)(&d1_lds[e4 * 4]);
            s = fmaf(c[e4 * 4 + 0], dv.x, s);
            s = fmaf(c[e4 * 4 + 1], dv.y, s);
            s = fmaf(c[e4 * 4 + 2], dv.z, s);
            s = fmaf(c[e4 * 4 + 3], dv.w, s);
        }
        d0 = (1.0f / 8192.0f) / (s + 1e-8f);
        d0_lds[tid] = d0;
        __syncthreads();

        // phase 2: colsum[pe] over this block's 256 tokens (quarter pq)
        float cs = 0.f;
        const float* rowp = &tileT[pe][pq * 64];
        const float* d0p  = &d0_lds[pq * 64];
#pragma unroll
        for (int j = 0; j < 16; j++) {
            float4 cv = *(const float4*)(rowp + j * 4);
            float4 dv = *(const float4*)(d0p + j * 4);
            cs = fmaf(cv.x, dv.x, cs);
            cs = fmaf(cv.y, dv.y, cs);
            cs = fmaf(cv.z, dv.z, cs);
            cs = fmaf(cv.w, dv.w, cs);
        }
        pl[pq][pe] = cs;
        __syncthreads();

        // hierarchical cross-block all-reduce (value-signaling on data)
        if (tid < 64) {
            float S = pl[0][tid] + pl[1][tid] + pl[2][tid] + pl[3][tid];
            __hip_atomic_store(&sd1[(size_t)(iter * SINK_BLOCKS + bid) * 64 + tid], S,
                               __ATOMIC_RELAXED, __HIP_MEMORY_SCOPE_AGENT);
            if (bid < 8) {   // leader: reduce own group of 4 blocks
                const float* b0 = sd1 + ((size_t)iter * SINK_BLOCKS + bid * 4) * 64 + tid;
                float v[4]; bool ok = false; int gg = 0;
                while (!ok && gg++ < (1 << 20)) {
                    ok = true;
#pragma unroll
                    for (int j = 0; j < 4; j++)
                        v[j] = __hip_atomic_load(b0 + j * 64, __ATOMIC_RELAXED,
                                                 __HIP_MEMORY_SCOPE_AGENT);
#pragma unroll
                    for (int j = 0; j < 4; j++) ok = ok && (v[j] > 0.f);
                }
                float L = (v[0] + v[1]) + (v[2] + v[3]);
                __hip_atomic_store(&sd2[(size_t)(iter * 8 + bid) * 64 + tid], L,
                                   __ATOMIC_RELAXED, __HIP_MEMORY_SCOPE_AGENT);
            }
            const float* c0 = sd2 + (size_t)iter * 8 * 64 + tid;
            float w[8]; bool ok2 = false; int g2 = 0;
            while (!ok2 && g2++ < (1 << 20)) {
                ok2 = true;
#pragma unroll
                for (int j = 0; j < 8; j++)
                    w[j] = __hip_atomic_load(c0 + j * 64, __ATOMIC_RELAXED,
                                             __HIP_MEMORY_SCOPE_AGENT);
#pragma unroll
                for (int j = 0; j < 8; j++) ok2 = ok2 && (w[j] > 0.f);
            }
            float S2 = ((w[0] + w[1]) + (w[2] + w[3])) + ((w[4] + w[5]) + (w[6] + w[7]));
            d1_lds[tid] = (1.0f / 64.0f) / (S2 + 1e-8f);
        }
        __syncthreads();
    }

    // argmax_e of d1[e]*c[e]*d0 (first max wins, like jnp.argmax)
    float best = -1.0f; int bi = 0;
#pragma unroll
    for (int e4 = 0; e4 < 16; e4++) {
        float4 dv = *(const float4*)(&d1_lds[e4 * 4]);
        float vv0 = (dv.x * c[e4 * 4 + 0]) * d0;
        float vv1 = (dv.y * c[e4 * 4 + 1]) * d0;
        float vv2 = (dv.z * c[e4 * 4 + 2]) * d0;
        float vv3 = (dv.w * c[e4 * 4 + 3]) * d0;
        if (vv0 > best) { best = vv0; bi = e4 * 4 + 0; }
        if (vv1 > best) { best = vv1; bi = e4 * 4 + 1; }
        if (vv2 > best) { best = vv2; bi = e4 * 4 + 2; }
        if (vv3 > best) { best = vv3; bi = e4 * 4 + 3; }
    }
    idx[t] = (float)bi;
}

extern "C" void kernel_launch(void* const* d_in, const int* in_sizes, int n_in,
                              void* d_out, int out_size, void* d_ws, size_t ws_size,
                              hipStream_t stream)
{
    (void)in_sizes; (void)n_in; (void)out_size; (void)ws_size;
    const float* hs = (const float*)d_in[0];   // 8192 x 2048 f32
    const float* W  = (const float*)d_in[1];   // 64 x 2048 f32
    float* out      = (float*)d_out;           // [logits | affinities | idx]

    bf16_t* wsw  = (bf16_t*)d_ws;                    // 512 KB prepped W (hi|lo)
    float*  part = (float*)d_ws + 131072;            // 4 MB: part[2][8192][64]
    float*  sd1  = part + (size_t)2 * T_TOKENS * 64; // 240 KB block partials
    float*  sd2  = sd1 + NITER * SINK_BLOCKS * 64;   // 60 KB leader sums

    prep_whl<<<128, 256, 0, stream>>>(W, wsw);
    gemm_splitk<<<512, 256, 0, stream>>>(hs, wsw, part);
    sinkhorn_v6<<<SINK_BLOCKS, 256, 0, stream>>>(part, out, sd1, sd2);
}